// Round 11
// baseline (67.580 us; speedup 1.0000x reference)
//
#include <hip/hip_runtime.h>

#define TT 16384
#define DD 2048
#define EE 64
#define NBLK 512

typedef __attribute__((ext_vector_type(8))) short bf16x8;
typedef __attribute__((ext_vector_type(8))) unsigned short ushort8;
typedef __attribute__((ext_vector_type(4))) float f32x4;
typedef __attribute__((ext_vector_type(16))) float f32x16;

__device__ __forceinline__ unsigned short bf16_rne(float f) {
    unsigned u = __float_as_uint(f);
    return (unsigned short)((u + 0x7FFFu + ((u >> 16) & 1u)) >> 16);
}
__device__ __forceinline__ float bf16_f32(unsigned short h) {
    return __uint_as_float(((unsigned)h) << 16);
}
__device__ __forceinline__ unsigned cvt_pk(float lo, float hi) {
    unsigned r;
    asm("v_cvt_pk_bf16_f32 %0, %1, %2" : "=v"(r) : "v"(lo), "v"(hi));
    return r;
}
__device__ __forceinline__ bf16x8 pack4(unsigned a, unsigned b, unsigned c, unsigned d) {
    union { unsigned u[4]; bf16x8 v; } t;
    t.u[0] = a; t.u[1] = b; t.u[2] = c; t.u[3] = d;
    return t.v;
}
__device__ __forceinline__ void gload16(void* lds, const void* g) {
    __builtin_amdgcn_global_load_lds(
        (const __attribute__((address_space(1))) unsigned int*)g,
        (__attribute__((address_space(3))) unsigned int*)lds, 16, 0, 0);
}
#define SB0() __builtin_amdgcn_sched_barrier(0)

// ---------------------------------------------------------------------------
// W [2048][64] f32 -> wpack: 32x32x16 A-fragments per 16-k chunk t=0..127.
// frag_id = t*4 + m*2 + h ; wpack[frag_id*512 + lane*8 + j] = bf16(hi/lo) of
//   wg[(t*16 + (lane>>5)*8 + j)*64 + m*32 + (lane&31)]
// Block 0 zeros the global bins + completion counter.
__global__ __launch_bounds__(256)
void wconv(const float* __restrict__ wg, unsigned short* __restrict__ wpack,
           float* __restrict__ gbins, unsigned* __restrict__ cnt) {
    if (blockIdx.x == 0) {
        if (threadIdx.x < 64) gbins[threadIdx.x] = 0.0f;
        if (threadIdx.x == 64) *cnt = 0u;
    }
    const int g = (int)blockIdx.x * 256 + threadIdx.x;
    const int t = g >> 8, m = (g >> 7) & 1, h = (g >> 6) & 1, lane = g & 63;
    const int e = m * 32 + (lane & 31);
    const int ks = t * 16 + (lane >> 5) * 8;
    ushort8 v;
#pragma unroll
    for (int j = 0; j < 8; ++j) {
        const float f = wg[(size_t)(ks + j) * EE + e];
        const unsigned short hi = bf16_rne(f);
        v[j] = h ? bf16_rne(f - bf16_f32(hi)) : hi;
    }
    *(ushort8*)(wpack + (size_t)g * 8) = v;
}

// ---------------------------------------------------------------------------
// Fused gate GEMM (32x32x16 bf16x3).  Block = 256 thr = 4 waves on the same
// 32 tokens; wave q owns the k-quarter of each BK=128 step.  16 steps.
// x staged via global_load_lds, 1 KB contiguous per instruction; double-
// buffered.  Every load group's FIFO position pinned with sched_barrier(0)
// so counted vmcnt drains are exact.  Per step:
//   [loadW(s+1) | compute(s)] bar | stage(s+2) vmcnt(12) | bar.
// R10 bug fixed here: K-reduce overlay stride was 20 floats/lane but each
// lane stores 32 (acc[2][16]) -> cross-lane corruption.  Stride now 36.
__global__ __launch_bounds__(256, 3)
void gate_fused(const float* __restrict__ x, const unsigned short* __restrict__ wpack,
                const float* __restrict__ loads, float* __restrict__ out,
                float* __restrict__ gbins, unsigned* __restrict__ cnt) {
    __shared__ __align__(16) float buf[2][4096];  // 32 KB: 2 x (32 rows x 128 f)
    __shared__ float bins[64];

    const int tid = threadIdx.x, lane = tid & 63, q = tid >> 6;  // q: k-quarter
    const int tb = (int)blockIdx.x;
    const int tok = lane & 31, hi5 = lane >> 5;

    f32x16 acc[2];
#pragma unroll
    for (int m = 0; m < 2; ++m)
#pragma unroll
        for (int r = 0; r < 16; ++r) acc[m][r] = 0.0f;

    // stage step s (128 k-floats x 32 rows = 16 KB) into buf[b]; 4 instrs/wave,
    // each 1 KB contiguous (rows 2i,2i+1).  Source unit pre-swizzled by r&7.
    auto stage_x = [&](int s, int b) {
#pragma unroll
        for (int j = 0; j < 4; ++j) {
            const int i = q * 4 + j;
            const int r = 2 * i + hi5;
            const int swz = (lane & 31) ^ (r & 7);
            gload16(&buf[b][i * 256],
                    x + (size_t)(tb * 32 + r) * DD + s * 128 + swz * 4);
        }
    };
    // 8 W-frags for step s (this wave's 2 chunks): [kc][m*2+h], 16 B/lane.
    auto loadW = [&](int s, bf16x8 (&W)[8]) {
        const unsigned short* base =
            wpack + (size_t)(s * 8 + q * 2) * 2048 + lane * 8;
#pragma unroll
        for (int f = 0; f < 8; ++f)
            W[f] = *(const bf16x8*)(base + (size_t)f * 512);
    };
    auto compute = [&](int b, bf16x8 (&W)[8]) {
        const float* rowp = &buf[b][tok * 128];
        const int sw = tok & 7;
#pragma unroll
        for (int kc = 0; kc < 2; ++kc) {
            const int u0 = (q * 2 + kc) * 4 + hi5 * 2;
            const f32x4 va = *(const f32x4*)(rowp + (u0 ^ sw) * 4);
            const f32x4 vb = *(const f32x4*)(rowp + ((u0 + 1) ^ sw) * 4);
            const float cf[8] = {va.x, va.y, va.z, va.w, vb.x, vb.y, vb.z, vb.w};
            unsigned ph[4], pl[4];
#pragma unroll
            for (int j = 0; j < 4; ++j) {
                ph[j] = cvt_pk(cf[2 * j], cf[2 * j + 1]);
                const float h0 = __uint_as_float(ph[j] << 16);
                const float h1 = __uint_as_float(ph[j] & 0xFFFF0000u);
                pl[j] = cvt_pk(cf[2 * j] - h0, cf[2 * j + 1] - h1);
            }
            const bf16x8 bhi = pack4(ph[0], ph[1], ph[2], ph[3]);
            const bf16x8 blo = pack4(pl[0], pl[1], pl[2], pl[3]);
            acc[0] = __builtin_amdgcn_mfma_f32_32x32x16_bf16(W[kc * 4 + 0], bhi, acc[0], 0, 0, 0);
            acc[0] = __builtin_amdgcn_mfma_f32_32x32x16_bf16(W[kc * 4 + 0], blo, acc[0], 0, 0, 0);
            acc[0] = __builtin_amdgcn_mfma_f32_32x32x16_bf16(W[kc * 4 + 1], bhi, acc[0], 0, 0, 0);
            acc[1] = __builtin_amdgcn_mfma_f32_32x32x16_bf16(W[kc * 4 + 2], bhi, acc[1], 0, 0, 0);
            acc[1] = __builtin_amdgcn_mfma_f32_32x32x16_bf16(W[kc * 4 + 2], blo, acc[1], 0, 0, 0);
            acc[1] = __builtin_amdgcn_mfma_f32_32x32x16_bf16(W[kc * 4 + 3], bhi, acc[1], 0, 0, 0);
        }
    };

    bf16x8 WA[8], WB[8];
    // prologue, each group FIFO-pinned: [st0][W0][st1]; vmcnt(4) leaves st1.
    stage_x(0, 0);
    SB0();
    loadW(0, WA);
    SB0();
    stage_x(1, 1);
    SB0();
    asm volatile("s_waitcnt vmcnt(4)" ::: "memory");  // drain st0 + W0
    SB0();
    __builtin_amdgcn_s_barrier();
    SB0();

#pragma unroll 1
    for (int s = 0; s < 16; ++s) {
        if (s < 15) {
            if (s & 1) loadW(s + 1, WA); else loadW(s + 1, WB);
        }
        if (s & 1) compute(1, WB); else compute(0, WA);
        __builtin_amdgcn_s_barrier();          // all reads of buf[s&1] done
        SB0();
        if (s < 14) stage_x(s + 2, s & 1);
        if (s < 14) {
            // FIFO: [st(s+1) 4][W(s+1) 8][st(s+2) 4] -> drain st(s+1) exactly
            asm volatile("s_waitcnt vmcnt(12)" ::: "memory");
        } else {
            // s=14: FIFO [st15 4][W15 8] -> drain st15, keep W15.  s=15: no-op.
            asm volatile("s_waitcnt vmcnt(8)" ::: "memory");
        }
        SB0();
        __builtin_amdgcn_s_barrier();          // buf[(s+1)&1] ready
        SB0();
    }

    // ---- deterministic 4-way K reduce through buf overlay ----------------
    // overlay [3][64][36]: 36-float stride per lane (32 stored + 4 pad).
    float* ov = (float*)buf;
    if (q != 0) {
        float* p = ov + (size_t)(q - 1) * 2304 + lane * 36;
#pragma unroll
        for (int m = 0; m < 2; ++m)
#pragma unroll
            for (int pp = 0; pp < 4; ++pp) {
                const f32x4 t_ = {acc[m][pp * 4], acc[m][pp * 4 + 1],
                                  acc[m][pp * 4 + 2], acc[m][pp * 4 + 3]};
                *(f32x4*)(p + m * 16 + pp * 4) = t_;
            }
    }
    __syncthreads();
    if (q != 0) return;

#pragma unroll 1
    for (int qq = 0; qq < 3; ++qq) {
        const float* p = ov + (size_t)qq * 2304 + lane * 36;
#pragma unroll
        for (int m = 0; m < 2; ++m)
#pragma unroll
            for (int pp = 0; pp < 4; ++pp) {
                const f32x4 t_ = *(const f32x4*)(p + m * 16 + pp * 4);
#pragma unroll
                for (int j = 0; j < 4; ++j) acc[m][pp * 4 + j] += t_[j];
            }
    }

    // ---- top-2 (biased): lane holds e = m*32 + (r&3) + 8*(r>>2) + 4*hi5 --
    float v1 = -3.4e38f, u1 = 0.0f, v2 = -3.4e38f, u2 = 0.0f;
    int i1 = 0x7fffffff, i2 = 0x7fffffff;
#pragma unroll
    for (int m = 0; m < 2; ++m)
#pragma unroll
        for (int r = 0; r < 16; ++r) {
            const int e = m * 32 + (r & 3) + 8 * (r >> 2) + 4 * hi5;
            const float u = acc[m][r];
            const float b = u - (loads[e] - 0.015625f) * 2.0f;
            if ((b > v1) || (b == v1 && e < i1)) {
                v2 = v1; u2 = u1; i2 = i1;
                v1 = b;  u1 = u;  i1 = e;
            } else if ((b > v2) || (b == v2 && e < i2)) {
                v2 = b; u2 = u; i2 = e;
            }
        }
    {   // merge lane <-> lane+32 (same token, other expert rows)
        const float ov1 = __shfl_xor(v1, 32), ou1 = __shfl_xor(u1, 32);
        const float ov2 = __shfl_xor(v2, 32), ou2 = __shfl_xor(u2, 32);
        const int oi1 = __shfl_xor(i1, 32), oi2 = __shfl_xor(i2, 32);
        if ((ov1 > v1) || (ov1 == v1 && oi1 < i1)) {
            if ((v1 > ov2) || (v1 == ov2 && i1 < oi2)) { v2 = v1; u2 = u1; i2 = i1; }
            else                                        { v2 = ov2; u2 = ou2; i2 = oi2; }
            v1 = ov1; u1 = ou1; i1 = oi1;
        } else if ((ov1 > v2) || (ov1 == v2 && oi1 < i2)) {
            v2 = ov1; u2 = ou1; i2 = oi1;
        }
    }

    bins[lane] = 0.0f;
    if (lane < 32) {
        const int tg = tb * 32 + tok;
        const float mx = fmaxf(u1, u2);
        const float e1 = __expf(u1 - mx), e2 = __expf(u2 - mx);
        const float w1 = e1 / (e1 + e2), w2 = e2 / (e1 + e2);
        *(float2*)(out + 2 * tg) = make_float2(w1, w2);
        *(float2*)(out + 2 * TT + 2 * tg) = make_float2((float)i1, (float)i2);
        atomicAdd(&bins[i1], w1);
        atomicAdd(&bins[i2], w2);
    }
    atomicAdd(&gbins[lane], bins[lane]);
    __threadfence();
    unsigned old = 0;
    if (lane == 0) old = atomicAdd(cnt, 1u);
    old = __shfl((int)old, 0);
    if (old == NBLK - 1) {
        __threadfence();
        const float tot = atomicAdd(&gbins[lane], 0.0f);
        out[4 * TT + lane] = 0.9f * loads[lane] + 0.1f * (tot * (1.0f / 16384.0f));
    }
}

// ---------------------------------------------------------------------------
extern "C" void kernel_launch(void* const* d_in, const int* in_sizes, int n_in,
                              void* d_out, int out_size, void* d_ws, size_t ws_size,
                              hipStream_t stream) {
    const float* x = (const float*)d_in[0];      // [16384, 2048]
    const float* wg = (const float*)d_in[1];     // [2048, 64]
    const float* loads = (const float*)d_in[2];  // [64]
    float* out = (float*)d_out;

    unsigned short* wpack = (unsigned short*)d_ws;           // 512 KB
    float* gbins = (float*)(wpack + (size_t)128 * 4 * 512);  // [64]
    unsigned* cnt = (unsigned*)(gbins + 64);                 // [1]

    hipLaunchKernelGGL(wconv, dim3(128), dim3(256), 0, stream, wg, wpack, gbins, cnt);
    hipLaunchKernelGGL(gate_fused, dim3(NBLK), dim3(256), 0, stream,
                       x, wpack, loads, out, gbins, cnt);
}

// Round 12
// 66.017 us; speedup vs baseline: 1.0237x; 1.0237x over previous
//
#include <hip/hip_runtime.h>

#define TT 16384
#define DD 2048
#define EE 64
#define NPUB 1024   // 512 blocks x 2 publishing waves

typedef __attribute__((ext_vector_type(8))) short bf16x8;
typedef __attribute__((ext_vector_type(8))) unsigned short ushort8;
typedef __attribute__((ext_vector_type(4))) float f32x4;

__device__ __forceinline__ unsigned short bf16_rne(float f) {
    unsigned u = __float_as_uint(f);
    return (unsigned short)((u + 0x7FFFu + ((u >> 16) & 1u)) >> 16);
}
__device__ __forceinline__ float bf16_f32(unsigned short h) {
    return __uint_as_float(((unsigned)h) << 16);
}
__device__ __forceinline__ unsigned cvt_pk(float lo, float hi) {
    unsigned r;
    asm("v_cvt_pk_bf16_f32 %0, %1, %2" : "=v"(r) : "v"(lo), "v"(hi));
    return r;  // low16 = bf16(lo), high16 = bf16(hi)
}
__device__ __forceinline__ bf16x8 pack4(unsigned a, unsigned b, unsigned c, unsigned d) {
    union { unsigned u[4]; bf16x8 v; } t;
    t.u[0] = a; t.u[1] = b; t.u[2] = c; t.u[3] = d;
    return t.v;
}
__device__ __forceinline__ void gload16(void* lds, const void* g) {
    __builtin_amdgcn_global_load_lds(
        (const __attribute__((address_space(1))) unsigned int*)g,
        (__attribute__((address_space(3))) unsigned int*)lds, 16, 0, 0);
}

// ---------------------------------------------------------------------------
// W [2048][64] f32 -> wpack: A-fragments in exact load order (R5 layout).
// wpack[K0][h][m][lane][j] = bf16 hi/lo of wg[(K0*32+(lane>>4)*8+j)*64 + m*16+(lane&15)]
// Block 0 zeros the global bins + completion counter.
__global__ __launch_bounds__(256)
void wconv(const float* __restrict__ wg, unsigned short* __restrict__ wpack,
           float* __restrict__ gbins, unsigned* __restrict__ cnt) {
    if (blockIdx.x == 0) {
        if (threadIdx.x < 64) gbins[threadIdx.x] = 0.0f;
        if (threadIdx.x == 64) *cnt = 0u;
    }
    const int t = (int)blockIdx.x * 256 + threadIdx.x;  // 32768 threads
    const int K0 = t >> 9, h = (t >> 8) & 1, m = (t >> 6) & 3, lane = t & 63;
    const int e = m * 16 + (lane & 15);
    const int ks = K0 * 32 + (lane >> 4) * 8;
    ushort8 v;
#pragma unroll
    for (int j = 0; j < 8; ++j) {
        const float f = wg[(size_t)(ks + j) * EE + e];
        const unsigned short hi = bf16_rne(f);
        v[j] = h ? bf16_rne(f - bf16_f32(hi)) : hi;
    }
    *(ushort8*)(wpack + ((size_t)(K0 * 8 + h * 4 + m) * 64 + lane) * 8) = v;
}

// ---------------------------------------------------------------------------
// R5's gate (best verified: 45.5 us total) with the bin tail fused in:
// 512 thr = 8 waves = 2 token-groups (16 tokens) x 4-way K-split.
// Grid 512 = 2 blocks/CU.  x: global_load_lds 3-ring (16 KB/step, source-side
// XOR swizzle, linear LDS).  W: 2-slot register ring from wpack (L2-hot).
// Counted vmcnt(10).  Epilogue publishes bins via device-scope atomics; the
// last of the 1024 publisher waves computes the EMA (R8-verified mechanism).
__global__ __launch_bounds__(512, 4)
void gate_fused(const float* __restrict__ x, const unsigned short* __restrict__ wpack,
                const float* __restrict__ loads, float* __restrict__ out,
                float* __restrict__ gbins, unsigned* __restrict__ cnt) {
    __shared__ __align__(16) float arena[3 * 4096];  // 48 KB: 3-ring, 16 KB/step
    __shared__ float bins[2][64];

    const int tid = threadIdx.x, lane = tid & 63, w = tid >> 6;
    const int tg = w >> 2, q = w & 3;   // token-group, K-quarter
    const int tb = (int)blockIdx.x;

    f32x4 acc[4] = {{0,0,0,0},{0,0,0,0},{0,0,0,0},{0,0,0,0}};

    // stage step s (k = qw*512 + s*32, all 32 tokens, 4 windows) into rb
    auto stage_x = [&](int s, float* rb) {
#pragma unroll
        for (int i = 0; i < 2; ++i) {
            const int n = (w << 1) | i;      // 0..15
            const int qw = n >> 2, g = n & 3;
            const int rowp = lane >> 3;      // 0..7
            const int row = g * 8 + rowp;    // 0..31
            const int c = (lane & 7) ^ rowp; // source-side chunk swizzle
            gload16(rb + qw * 1024 + g * 256,
                    x + (size_t)(tb * 32 + row) * DD + qw * 512 + s * 32 + c * 4);
        }
    };
    auto loadW = [&](int t, bf16x8 (&wh)[4], bf16x8 (&wl)[4]) {
        const unsigned short* base = wpack + (size_t)(q * 16 + t) * 4096 + lane * 8;
#pragma unroll
        for (int m = 0; m < 4; ++m) {
            wh[m] = *(const bf16x8*)(base + (size_t)m * 512);
            wl[m] = *(const bf16x8*)(base + (size_t)(4 + m) * 512);
        }
    };
    auto compute = [&](const float* rb, bf16x8 (&wh)[4], bf16x8 (&wl)[4]) {
        const float* xq = rb + q * 1024;
        const int row = tg * 16 + (lane & 15);
        const int kgc = (lane >> 4) << 1;
        const int sw = row & 7;
        const f32x4 va = *(const f32x4*)(xq + row * 32 + ((kgc) ^ sw) * 4);
        const f32x4 vb = *(const f32x4*)(xq + row * 32 + ((kgc + 1) ^ sw) * 4);
        const float cf[8] = {va.x, va.y, va.z, va.w, vb.x, vb.y, vb.z, vb.w};
        unsigned ph[4], pl[4];
#pragma unroll
        for (int j = 0; j < 4; ++j) {
            ph[j] = cvt_pk(cf[2 * j], cf[2 * j + 1]);
            const float h0 = __uint_as_float(ph[j] << 16);
            const float h1 = __uint_as_float(ph[j] & 0xFFFF0000u);
            pl[j] = cvt_pk(cf[2 * j] - h0, cf[2 * j + 1] - h1);
        }
        const bf16x8 bhi = pack4(ph[0], ph[1], ph[2], ph[3]);
        const bf16x8 blo = pack4(pl[0], pl[1], pl[2], pl[3]);
#pragma unroll
        for (int m = 0; m < 4; ++m) {
            acc[m] = __builtin_amdgcn_mfma_f32_16x16x32_bf16(wh[m], bhi, acc[m], 0, 0, 0);
            acc[m] = __builtin_amdgcn_mfma_f32_16x16x32_bf16(wh[m], blo, acc[m], 0, 0, 0);
            acc[m] = __builtin_amdgcn_mfma_f32_16x16x32_bf16(wl[m], bhi, acc[m], 0, 0, 0);
        }
    };

    float *p0 = arena, *p1 = arena + 4096, *p2 = arena + 8192;
    bf16x8 whA[4], wlA[4], whB[4], wlB[4];

    stage_x(0, p0);
    stage_x(1, p1);
    loadW(0, whA, wlA);
    asm volatile("s_waitcnt vmcnt(10)" ::: "memory");
    __builtin_amdgcn_s_barrier();

#pragma unroll 1
    for (int s = 0; s < 14; s += 2) {
        stage_x(s + 2, p2);
        loadW(s + 1, whB, wlB);
        compute(p0, whA, wlA);
        asm volatile("s_waitcnt vmcnt(10)" ::: "memory");
        __builtin_amdgcn_s_barrier();
        { float* t_ = p0; p0 = p1; p1 = p2; p2 = t_; }

        stage_x(s + 3, p2);
        loadW(s + 2, whA, wlA);
        compute(p0, whB, wlB);
        asm volatile("s_waitcnt vmcnt(10)" ::: "memory");
        __builtin_amdgcn_s_barrier();
        { float* t_ = p0; p0 = p1; p1 = p2; p2 = t_; }
    }
    loadW(15, whB, wlB);
    compute(p0, whA, wlA);               // step 14
    asm volatile("s_waitcnt vmcnt(8)" ::: "memory");
    __builtin_amdgcn_s_barrier();
    compute(p1, whB, wlB);               // step 15

    // ---- K-split reduction through arena overlay (stride 20: no conflicts)
    __syncthreads();                     // all ds_reads of step 15 done
    float* accb = arena;                 // [3 q'][2 tg][64 lane][20]
    if (q != 0) {
#pragma unroll
        for (int m = 0; m < 4; ++m)
            *(f32x4*)(accb + ((size_t)((q - 1) * 128 + tg * 64 + lane) * 20 + m * 4)) = acc[m];
    }
    __syncthreads();
    if (q != 0) return;

    f32x4 r[4];
#pragma unroll
    for (int m = 0; m < 4; ++m) {
        f32x4 s_ = acc[m];
#pragma unroll
        for (int qq = 0; qq < 3; ++qq) {
            const f32x4 t_ =
                *(const f32x4*)(accb + ((size_t)(qq * 128 + tg * 64 + lane) * 20 + m * 4));
            s_.x += t_.x; s_.y += t_.y; s_.z += t_.z; s_.w += t_.w;
        }
        r[m] = s_;
    }

    // ---- top-2 (biased): lane holds e = m*16 + (lane>>4)*4 + rr ----------
    const int col = lane & 15;
    const int tok = tb * 32 + tg * 16 + col;
    const int erow = (lane >> 4) * 4;
    float v1 = -3.4e38f, u1 = 0.0f, v2 = -3.4e38f, u2 = 0.0f;
    int i1 = 0x7fffffff, i2 = 0x7fffffff;
#pragma unroll
    for (int m = 0; m < 4; ++m)
#pragma unroll
        for (int rr = 0; rr < 4; ++rr) {
            const int e = m * 16 + erow + rr;
            const float u = r[m][rr];
            const float b = u - (loads[e] - 0.015625f) * 2.0f;
            if ((b > v1) || (b == v1 && e < i1)) {
                v2 = v1; u2 = u1; i2 = i1;
                v1 = b;  u1 = u;  i1 = e;
            } else if ((b > v2) || (b == v2 && e < i2)) {
                v2 = b; u2 = u; i2 = e;
            }
        }
#pragma unroll
    for (int s = 0; s < 2; ++s) {
        const int mask = 16 << s;
        const float ov1 = __shfl_xor(v1, mask), ou1 = __shfl_xor(u1, mask);
        const float ov2 = __shfl_xor(v2, mask), ou2 = __shfl_xor(u2, mask);
        const int oi1 = __shfl_xor(i1, mask), oi2 = __shfl_xor(i2, mask);
        if ((ov1 > v1) || (ov1 == v1 && oi1 < i1)) {
            if ((v1 > ov2) || (v1 == ov2 && i1 < oi2)) { v2 = v1; u2 = u1; i2 = i1; }
            else                                        { v2 = ov2; u2 = ou2; i2 = oi2; }
            v1 = ov1; u1 = ou1; i1 = oi1;
        } else if ((ov1 > v2) || (ov1 == v2 && oi1 < i2)) {
            v2 = ov1; u2 = ou1; i2 = oi1;
        }
    }

    bins[tg][lane] = 0.0f;
    if (lane < 16) {
        const float mx = fmaxf(u1, u2);
        const float e1 = __expf(u1 - mx), e2 = __expf(u2 - mx);
        const float w1 = e1 / (e1 + e2), w2 = e2 / (e1 + e2);
        *(float2*)(out + 2 * tok) = make_float2(w1, w2);
        *(float2*)(out + 2 * TT + 2 * tok) = make_float2((float)i1, (float)i2);
        atomicAdd(&bins[tg][i1], w1);
        atomicAdd(&bins[tg][i2], w2);
    }
    // ---- fused bin tail (R8-verified): publish + last-wave EMA -----------
    atomicAdd(&gbins[lane], bins[tg][lane]);
    __threadfence();
    unsigned old = 0;
    if (lane == 0) old = atomicAdd(cnt, 1u);
    old = __shfl((int)old, 0);
    if (old == NPUB - 1) {
        __threadfence();
        const float tot = atomicAdd(&gbins[lane], 0.0f);  // coherent read
        out[4 * TT + lane] = 0.9f * loads[lane] + 0.1f * (tot * (1.0f / 16384.0f));
    }
}

// ---------------------------------------------------------------------------
extern "C" void kernel_launch(void* const* d_in, const int* in_sizes, int n_in,
                              void* d_out, int out_size, void* d_ws, size_t ws_size,
                              hipStream_t stream) {
    const float* x = (const float*)d_in[0];      // [16384, 2048]
    const float* wg = (const float*)d_in[1];     // [2048, 64]
    const float* loads = (const float*)d_in[2];  // [64]
    float* out = (float*)d_out;

    unsigned short* wpack = (unsigned short*)d_ws;             // 512 KB
    float* gbins = (float*)(wpack + (size_t)64 * 8 * 64 * 8);  // [64]
    unsigned* cnt = (unsigned*)(gbins + 64);                   // [1]

    hipLaunchKernelGGL(wconv, dim3(128), dim3(256), 0, stream, wg, wpack, gbins, cnt);
    hipLaunchKernelGGL(gate_fused, dim3(512), dim3(512), 0, stream,
                       x, wpack, loads, out, gbins, cnt);
}

// Round 13
// 45.241 us; speedup vs baseline: 1.4938x; 1.4592x over previous
//
#include <hip/hip_runtime.h>

#define TT 16384
#define DD 2048
#define EE 64

typedef __attribute__((ext_vector_type(8))) short bf16x8;
typedef __attribute__((ext_vector_type(8))) unsigned short ushort8;
typedef __attribute__((ext_vector_type(4))) float f32x4;

__device__ __forceinline__ unsigned short bf16_rne(float f) {
    unsigned u = __float_as_uint(f);
    return (unsigned short)((u + 0x7FFFu + ((u >> 16) & 1u)) >> 16);
}
__device__ __forceinline__ float bf16_f32(unsigned short h) {
    return __uint_as_float(((unsigned)h) << 16);
}
__device__ __forceinline__ unsigned cvt_pk(float lo, float hi) {
    unsigned r;
    asm("v_cvt_pk_bf16_f32 %0, %1, %2" : "=v"(r) : "v"(lo), "v"(hi));
    return r;  // low16 = bf16(lo), high16 = bf16(hi)
}
__device__ __forceinline__ bf16x8 pack4(unsigned a, unsigned b, unsigned c, unsigned d) {
    union { unsigned u[4]; bf16x8 v; } t;
    t.u[0] = a; t.u[1] = b; t.u[2] = c; t.u[3] = d;
    return t.v;
}
__device__ __forceinline__ void gload16(void* lds, const void* g) {
    __builtin_amdgcn_global_load_lds(
        (const __attribute__((address_space(1))) unsigned int*)g,
        (__attribute__((address_space(3))) unsigned int*)lds, 16, 0, 0);
}

// ---------------------------------------------------------------------------
// W [2048][64] f32 -> wpack: A-fragments in exact load order (R5 layout).
// wpack[K0][h][m][lane][j] = bf16 hi/lo of wg[(K0*32+(lane>>4)*8+j)*64 + m*16+(lane&15)]
__global__ __launch_bounds__(256)
void wconv(const float* __restrict__ wg, unsigned short* __restrict__ wpack) {
    const int t = (int)blockIdx.x * 256 + threadIdx.x;  // 32768 threads
    const int K0 = t >> 9, h = (t >> 8) & 1, m = (t >> 6) & 3, lane = t & 63;
    const int e = m * 16 + (lane & 15);
    const int ks = K0 * 32 + (lane >> 4) * 8;
    ushort8 v;
#pragma unroll
    for (int j = 0; j < 8; ++j) {
        const float f = wg[(size_t)(ks + j) * EE + e];
        const unsigned short hi = bf16_rne(f);
        v[j] = h ? bf16_rne(f - bf16_f32(hi)) : hi;
    }
    *(ushort8*)(wpack + ((size_t)(K0 * 8 + h * 4 + m) * 64 + lane) * 8) = v;
}

// ---------------------------------------------------------------------------
// R5's gate verbatim (best verified: 45.5 us total).
// 512 thr = 8 waves = 2 token-groups (16 tokens) x 4-way K-split.
// Grid 512 = 2 blocks/CU.  x: global_load_lds 3-ring (16 KB/step, source-side
// XOR swizzle, linear LDS).  W: 2-slot register ring from wpack (L2-hot).
// Counted vmcnt(10).  Bins to binpart via plain stores (NO device atomics --
// R8/R11/R12 proved the atomic tail costs ~15-20 us).
__global__ __launch_bounds__(512, 4)
void gate_fused(const float* __restrict__ x, const unsigned short* __restrict__ wpack,
                const float* __restrict__ loads, float* __restrict__ out,
                float* __restrict__ binpart) {
    __shared__ __align__(16) float arena[3 * 4096];  // 48 KB: 3-ring, 16 KB/step
    __shared__ float bins[2][64];

    const int tid = threadIdx.x, lane = tid & 63, w = tid >> 6;
    const int tg = w >> 2, q = w & 3;   // token-group, K-quarter
    const int tb = (int)blockIdx.x;

    f32x4 acc[4] = {{0,0,0,0},{0,0,0,0},{0,0,0,0},{0,0,0,0}};

    auto stage_x = [&](int s, float* rb) {
#pragma unroll
        for (int i = 0; i < 2; ++i) {
            const int n = (w << 1) | i;      // 0..15
            const int qw = n >> 2, g = n & 3;
            const int rowp = lane >> 3;      // 0..7
            const int row = g * 8 + rowp;    // 0..31
            const int c = (lane & 7) ^ rowp; // source-side chunk swizzle
            gload16(rb + qw * 1024 + g * 256,
                    x + (size_t)(tb * 32 + row) * DD + qw * 512 + s * 32 + c * 4);
        }
    };
    auto loadW = [&](int t, bf16x8 (&wh)[4], bf16x8 (&wl)[4]) {
        const unsigned short* base = wpack + (size_t)(q * 16 + t) * 4096 + lane * 8;
#pragma unroll
        for (int m = 0; m < 4; ++m) {
            wh[m] = *(const bf16x8*)(base + (size_t)m * 512);
            wl[m] = *(const bf16x8*)(base + (size_t)(4 + m) * 512);
        }
    };
    auto compute = [&](const float* rb, bf16x8 (&wh)[4], bf16x8 (&wl)[4]) {
        const float* xq = rb + q * 1024;
        const int row = tg * 16 + (lane & 15);
        const int kgc = (lane >> 4) << 1;
        const int sw = row & 7;
        const f32x4 va = *(const f32x4*)(xq + row * 32 + ((kgc) ^ sw) * 4);
        const f32x4 vb = *(const f32x4*)(xq + row * 32 + ((kgc + 1) ^ sw) * 4);
        const float cf[8] = {va.x, va.y, va.z, va.w, vb.x, vb.y, vb.z, vb.w};
        unsigned ph[4], pl[4];
#pragma unroll
        for (int j = 0; j < 4; ++j) {
            ph[j] = cvt_pk(cf[2 * j], cf[2 * j + 1]);
            const float h0 = __uint_as_float(ph[j] << 16);
            const float h1 = __uint_as_float(ph[j] & 0xFFFF0000u);
            pl[j] = cvt_pk(cf[2 * j] - h0, cf[2 * j + 1] - h1);
        }
        const bf16x8 bhi = pack4(ph[0], ph[1], ph[2], ph[3]);
        const bf16x8 blo = pack4(pl[0], pl[1], pl[2], pl[3]);
#pragma unroll
        for (int m = 0; m < 4; ++m) {
            acc[m] = __builtin_amdgcn_mfma_f32_16x16x32_bf16(wh[m], bhi, acc[m], 0, 0, 0);
            acc[m] = __builtin_amdgcn_mfma_f32_16x16x32_bf16(wh[m], blo, acc[m], 0, 0, 0);
            acc[m] = __builtin_amdgcn_mfma_f32_16x16x32_bf16(wl[m], bhi, acc[m], 0, 0, 0);
        }
    };

    float *p0 = arena, *p1 = arena + 4096, *p2 = arena + 8192;
    bf16x8 whA[4], wlA[4], whB[4], wlB[4];

    stage_x(0, p0);
    stage_x(1, p1);
    loadW(0, whA, wlA);
    asm volatile("s_waitcnt vmcnt(10)" ::: "memory");
    __builtin_amdgcn_s_barrier();

#pragma unroll 1
    for (int s = 0; s < 14; s += 2) {
        stage_x(s + 2, p2);
        loadW(s + 1, whB, wlB);
        compute(p0, whA, wlA);
        asm volatile("s_waitcnt vmcnt(10)" ::: "memory");
        __builtin_amdgcn_s_barrier();
        { float* t_ = p0; p0 = p1; p1 = p2; p2 = t_; }

        stage_x(s + 3, p2);
        loadW(s + 2, whA, wlA);
        compute(p0, whB, wlB);
        asm volatile("s_waitcnt vmcnt(10)" ::: "memory");
        __builtin_amdgcn_s_barrier();
        { float* t_ = p0; p0 = p1; p1 = p2; p2 = t_; }
    }
    loadW(15, whB, wlB);
    compute(p0, whA, wlA);               // step 14
    asm volatile("s_waitcnt vmcnt(8)" ::: "memory");
    __builtin_amdgcn_s_barrier();
    compute(p1, whB, wlB);               // step 15

    // ---- K-split reduction through arena overlay (stride 20: no conflicts)
    __syncthreads();                     // all ds_reads of step 15 done
    float* accb = arena;                 // [3 q'][2 tg][64 lane][20]
    if (q != 0) {
#pragma unroll
        for (int m = 0; m < 4; ++m)
            *(f32x4*)(accb + ((size_t)((q - 1) * 128 + tg * 64 + lane) * 20 + m * 4)) = acc[m];
    }
    __syncthreads();
    if (q != 0) return;

    f32x4 r[4];
#pragma unroll
    for (int m = 0; m < 4; ++m) {
        f32x4 s_ = acc[m];
#pragma unroll
        for (int qq = 0; qq < 3; ++qq) {
            const f32x4 t_ =
                *(const f32x4*)(accb + ((size_t)(qq * 128 + tg * 64 + lane) * 20 + m * 4));
            s_.x += t_.x; s_.y += t_.y; s_.z += t_.z; s_.w += t_.w;
        }
        r[m] = s_;
    }

    // ---- top-2 (biased): lane holds e = m*16 + (lane>>4)*4 + rr ----------
    const int col = lane & 15;
    const int tok = tb * 32 + tg * 16 + col;
    const int erow = (lane >> 4) * 4;
    float v1 = -3.4e38f, u1 = 0.0f, v2 = -3.4e38f, u2 = 0.0f;
    int i1 = 0x7fffffff, i2 = 0x7fffffff;
#pragma unroll
    for (int m = 0; m < 4; ++m)
#pragma unroll
        for (int rr = 0; rr < 4; ++rr) {
            const int e = m * 16 + erow + rr;
            const float u = r[m][rr];
            const float b = u - (loads[e] - 0.015625f) * 2.0f;
            if ((b > v1) || (b == v1 && e < i1)) {
                v2 = v1; u2 = u1; i2 = i1;
                v1 = b;  u1 = u;  i1 = e;
            } else if ((b > v2) || (b == v2 && e < i2)) {
                v2 = b; u2 = u; i2 = e;
            }
        }
#pragma unroll
    for (int s = 0; s < 2; ++s) {
        const int mask = 16 << s;
        const float ov1 = __shfl_xor(v1, mask), ou1 = __shfl_xor(u1, mask);
        const float ov2 = __shfl_xor(v2, mask), ou2 = __shfl_xor(u2, mask);
        const int oi1 = __shfl_xor(i1, mask), oi2 = __shfl_xor(i2, mask);
        if ((ov1 > v1) || (ov1 == v1 && oi1 < i1)) {
            if ((v1 > ov2) || (v1 == ov2 && i1 < oi2)) { v2 = v1; u2 = u1; i2 = i1; }
            else                                        { v2 = ov2; u2 = ou2; i2 = oi2; }
            v1 = ov1; u1 = ou1; i1 = oi1;
        } else if ((ov1 > v2) || (ov1 == v2 && oi1 < i2)) {
            v2 = ov1; u2 = ou1; i2 = oi1;
        }
    }

    bins[tg][lane] = 0.0f;
    if (lane < 16) {
        const float mx = fmaxf(u1, u2);
        const float e1 = __expf(u1 - mx), e2 = __expf(u2 - mx);
        const float w1 = e1 / (e1 + e2), w2 = e2 / (e1 + e2);
        *(float2*)(out + 2 * tok) = make_float2(w1, w2);
        *(float2*)(out + 2 * TT + 2 * tok) = make_float2((float)i1, (float)i2);
        atomicAdd(&bins[tg][i1], w1);
        atomicAdd(&bins[tg][i2], w2);
    }
    binpart[(size_t)(tb * 2 + tg) * 64 + lane] = bins[tg][lane];
}

// ---------------------------------------------------------------------------
// Single merged finalize: 1 block x 1024 thr sums [1024][64] binpart rows in
// fixed order (deterministic tree) + EMA.  Replaces R5's finalize1+finalize2.
__global__ __launch_bounds__(1024)
void finalize(const float* __restrict__ binpart, const float* __restrict__ loads,
              float* __restrict__ out) {
    __shared__ float p[16][64];
    const int e = threadIdx.x & 63, sub = threadIdx.x >> 6;  // sub 0..15
    float s = 0.0f;
#pragma unroll
    for (int r = 0; r < 64; ++r)
        s += binpart[(size_t)(sub * 64 + r) * 64 + e];
    p[sub][e] = s;
    __syncthreads();
    if (sub == 0) {
        float tot = 0.0f;
#pragma unroll
        for (int k = 0; k < 16; ++k) tot += p[k][e];
        out[4 * TT + e] = 0.9f * loads[e] + 0.1f * (tot * (1.0f / 16384.0f));
    }
}

// ---------------------------------------------------------------------------
extern "C" void kernel_launch(void* const* d_in, const int* in_sizes, int n_in,
                              void* d_out, int out_size, void* d_ws, size_t ws_size,
                              hipStream_t stream) {
    const float* x = (const float*)d_in[0];      // [16384, 2048]
    const float* wg = (const float*)d_in[1];     // [2048, 64]
    const float* loads = (const float*)d_in[2];  // [64]
    float* out = (float*)d_out;

    unsigned short* wpack = (unsigned short*)d_ws;               // 512 KB
    float* binpart = (float*)(wpack + (size_t)64 * 8 * 64 * 8);  // [1024][64]

    hipLaunchKernelGGL(wconv, dim3(128), dim3(256), 0, stream, wg, wpack);
    hipLaunchKernelGGL(gate_fused, dim3(512), dim3(512), 0, stream,
                       x, wpack, loads, out, binpart);
    hipLaunchKernelGGL(finalize, dim3(1), dim3(1024), 0, stream,
                       binpart, loads, out);
}